// Round 4
// baseline (532.365 us; speedup 1.0000x reference)
//
#include <hip/hip_runtime.h>
#include <math.h>

// ---------------------------------------------------------------------------
// VQ-VAE forward.
// Encoder: 256-ch convs as implicit-GEMM MFMA with 2-term bf16 split inputs
// (3 passes: w1x1 + w1x2 + w2x1). Big convs split-K=2 with PLAIN-STORE
// per-kz partial buffers (no atomics, no memset). VQ: chunk-parallel partial
// argmin + reduce. Decoder: t1 + t2.
// R4: counted-vmcnt pipeline (T4): 2-deep register prefetch + raw s_barrier
//     with lgkmcnt(0)-only fence -> next-next chunk's global loads stay in
//     flight across the barrier (no vmcnt(0) drain per chunk). T5 setprio
//     around MFMA cluster. Applied to both split kernels, 1x1, and t1.
// ---------------------------------------------------------------------------

typedef unsigned int uint;
typedef unsigned short ushort_t;
using short8 = __attribute__((ext_vector_type(8))) short;
using f32x4  = __attribute__((ext_vector_type(4))) float;

static __device__ __forceinline__ int rfl(int x) { return __builtin_amdgcn_readfirstlane(x); }
static __device__ __forceinline__ ushort_t f2bf(float f) {
  uint u = __float_as_uint(f);
  return (ushort_t)((u + 0x7fffu + ((u >> 16) & 1u)) >> 16);  // RNE; finite inputs
}
static __device__ __forceinline__ float bf2f(ushort_t b) {
  return __uint_as_float(((uint)b) << 16);
}
static __device__ __forceinline__ void fence_lgkm_barrier() {
  asm volatile("s_waitcnt lgkmcnt(0)" ::: "memory");
  __builtin_amdgcn_s_barrier();
}

// ---------- weight prep ----------
__global__ void k_transpose_w(const float* __restrict__ w, float* __restrict__ wT, int CO, int CIKK) {
  int idx = blockIdx.x * 256 + threadIdx.x;
  if (idx >= CO * CIKK) return;
  int co = idx % CO, i = idx / CO;
  wT[idx] = w[co * CIKK + i];
}

// encoder MFMA weight pack: w[co][ci(256)][KH][KW] fp32 ->
// wp[chunk][coT(4)][pl(2)][row(64)][k(32)] bf16 split, chunk = tap*8 + cg
template<int KIND>  // 0: 4x4 (16 taps), 1: 3x3 (9 taps), 2: 1x1 (1 tap)
__global__ void k_prep_enc(const float* __restrict__ w, ushort_t* __restrict__ wp, int total) {
  int idx = blockIdx.x * 256 + threadIdx.x;
  if (idx >= total) return;
  int k = idx & 31, row = (idx >> 5) & 63, pl = (idx >> 11) & 1, coT = (idx >> 12) & 3, chunk = idx >> 14;
  int tap = chunk >> 3, cg = chunk & 7;
  int co = coT * 64 + row, ci = cg * 32 + k;
  int ky, kx, KK, KW;
  if (KIND == 0)      { ky = tap >> 2; kx = tap & 3;       KK = 16; KW = 4; }
  else if (KIND == 1) { ky = tap / 3;  kx = tap - ky * 3;  KK = 9;  KW = 3; }
  else                { ky = 0;        kx = 0;             KK = 1;  KW = 1; }
  float v = w[(co * 256 + ci) * KK + ky * KW + kx];
  ushort_t b0 = f2bf(v);
  wp[idx] = pl ? f2bf(v - bf2f(b0)) : b0;
}

// t1_w [ci][co][ky][kx] -> bf16 [par][tap][c8][co][kk32]
__global__ void k_prep_t1w(const float* __restrict__ w, ushort_t* __restrict__ wb) {
  int idx = blockIdx.x * 256 + threadIdx.x;  // 1048576
  int kk  = idx & 31;
  int co  = (idx >> 5) & 255;
  int c8  = (idx >> 13) & 7;
  int tap = (idx >> 16) & 3;
  int par = idx >> 18;
  int ry = par & 1, rx = (par >> 1) & 1;
  int a = tap >> 1, b = tap & 1;
  int ky = ((ry + 1) & 1) + 2 * a;
  int kx = ((rx + 1) & 1) + 2 * b;
  int ci = c8 * 32 + kk;
  wb[idx] = f2bf(w[((ci * 256 + co) << 4) + ky * 4 + kx]);
}

// t2_w [ci(256)][co(3)][4][4] -> bf16 [par(4)][chunk(32)][co16][k32]
__global__ void k_prep_t2w(const float* __restrict__ w, ushort_t* __restrict__ wb) {
  int idx = blockIdx.x * 256 + threadIdx.x;  // 65536
  int k = idx & 31, co = (idx >> 5) & 15, chunk = (idx >> 9) & 31, par = idx >> 14;
  int tap = chunk >> 3, cg = chunk & 7;
  int a = tap >> 1, b = tap & 1;
  int ry = par & 1, rx = (par >> 1) & 1;
  int ky = ((ry + 1) & 1) + 2 * a;
  int kx = ((rx + 1) & 1) + 2 * b;
  int ci = cg * 32 + k;
  float v = (co < 3) ? w[((ci * 3 + co) << 4) + ky * 4 + kx] : 0.f;
  wb[idx] = f2bf(v);
}

// cnorm[j] = sum_c cb[j][c]^2
__global__ void k_prep_cb(const float* __restrict__ cb, float* __restrict__ cnorm) {
  int idx = blockIdx.x * 256 + threadIdx.x;
  if (idx < 512) {
    float s = 0.f;
    for (int c = 0; c < 64; ++c) { float v = cb[idx * 64 + c]; s = fmaf(v, v, s); }
    cnorm[idx] = s;
  }
}

// ---------- conv1: 3->256, 4x4 s2 p1, relu, output split-bf16 NHWC ----------
__global__ __launch_bounds__(256) void k_conv1_split(
    const float* __restrict__ in, ushort_t* __restrict__ o0, ushort_t* __restrict__ o1,
    const float* __restrict__ wT, const float* __restrict__ bias)
{
  __shared__ float s_in[3 * 360];  // parity-split cols, pitch 20 (2-way free)
  const int tid = threadIdx.x;
  const int lane = tid & 63;
  const int wv = rfl(tid >> 6);
  const int px = lane & 7, py = lane >> 3;
  const int tx = blockIdx.x & 7, ty = blockIdx.x >> 3;
  const int X = tx * 8, Y = ty * 8;
  const int cob = blockIdx.y * 64 + wv * 16;
  const int n = blockIdx.z;
  float acc[16];
#pragma unroll
  for (int i = 0; i < 16; ++i) acc[i] = bias[cob + i];
  const float* inN = in + (size_t)n * 3 * 16384;
  for (int e = tid; e < 3 * 360; e += 256) {
    int col2 = e % 20; int t = e / 20; int row = t % 18; int ci = t / 18;
    int pr = col2 / 10, hc = col2 % 10, ixl = 2 * hc + pr;
    int iy = 2 * Y - 1 + row, ix = 2 * X - 1 + ixl;
    float v = 0.f;
    if (ixl < 18 && (unsigned)iy < 128u && (unsigned)ix < 128u)
      v = inN[ci * 16384 + iy * 128 + ix];
    s_in[e] = v;
  }
  __syncthreads();
  const float* wc = wT + cob;
#pragma unroll
  for (int c = 0; c < 3; ++c) {
    const float* base = s_in + c * 360 + py * 40 + px;
#pragma unroll
    for (int ky = 0; ky < 4; ++ky) {
#pragma unroll
      for (int kx = 0; kx < 4; ++kx) {
        float iv = base[ky * 20 + (kx & 1) * 10 + (kx >> 1)];
        const float* w = wc + (size_t)(c * 16 + ky * 4 + kx) * 256;  // uniform
#pragma unroll
        for (int i = 0; i < 16; ++i) acc[i] = fmaf(iv, w[i], acc[i]);
      }
    }
  }
  const int pxg = n * 4096 + (Y + py) * 64 + (X + px);
  uint p0[8], p1[8];
#pragma unroll
  for (int i = 0; i < 8; ++i) {
    float va = fmaxf(acc[2 * i], 0.f), vb = fmaxf(acc[2 * i + 1], 0.f);
    ushort_t a0 = f2bf(va), b0 = f2bf(vb);
    ushort_t a1 = f2bf(va - bf2f(a0)), b1 = f2bf(vb - bf2f(b0));
    p0[i] = (uint)a0 | ((uint)b0 << 16);
    p1[i] = (uint)a1 | ((uint)b1 << 16);
  }
  ushort_t* d0 = o0 + (size_t)pxg * 256 + cob;
  ushort_t* d1 = o1 + (size_t)pxg * 256 + cob;
  uint4 v0a; v0a.x = p0[0]; v0a.y = p0[1]; v0a.z = p0[2]; v0a.w = p0[3];
  uint4 v0b; v0b.x = p0[4]; v0b.y = p0[5]; v0b.z = p0[6]; v0b.w = p0[7];
  uint4 v1a; v1a.x = p1[0]; v1a.y = p1[1]; v1a.z = p1[2]; v1a.w = p1[3];
  uint4 v1b; v1b.x = p1[4]; v1b.y = p1[5]; v1b.z = p1[6]; v1b.w = p1[7];
  *(uint4*)d0 = v0a; *(uint4*)(d0 + 8) = v0b;
  *(uint4*)d1 = v1a; *(uint4*)(d1 + 8) = v1b;
}

// ---------- encoder implicit-GEMM MFMA, split-K=2, plain-store partial ------
// Block: 64co x 128px, 4 waves; wave: 64co x 32px = 4x2 of 16x16x32; 3 passes.
// grid (pxT 64, coT 4, kz 2); kz block z stores its partial at part + z*2^21.
// R4: 2-deep P/Q register prefetch; raw barrier with lgkmcnt-only fence so
// next-next chunk's loads stay in flight (counted vmcnt, no drain).
template<int KIND>  // 0: conv2 (128 chunks), 1: 3x3 (72 chunks)
__global__ __launch_bounds__(256) void k_enc_mfma_split(
    const ushort_t* __restrict__ x0, const ushort_t* __restrict__ x1,
    const ushort_t* __restrict__ wp, float* __restrict__ part)
{
  __shared__ ushort_t smem[2][12288];   // per buf: sA 4096 | sB 8192 (ushorts)
  const int tid = threadIdx.x, lane = tid & 63, wv = tid >> 6;
  const int l15 = lane & 15, q = lane >> 4;
  const int pxT = blockIdx.x, coT = blockIdx.y;
  constexpr int NCH = (KIND == 0) ? 128 : 72;
  const int CH0 = blockIdx.z * (NCH / 2), CH1 = CH0 + NCH / 2;
  f32x4 acc[4][2];
#pragma unroll
  for (int m = 0; m < 4; ++m)
#pragma unroll
    for (int n = 0; n < 2; ++n) acc[m][n] = (f32x4){0.f, 0.f, 0.f, 0.f};

  const int brow = tid >> 1, bhalf = tid & 1;
  const int bpx = pxT * 128 + brow;
  const int bimg = bpx >> 10, bp = bpx & 1023, bu = bp >> 5, bvc = bp & 31;

  // swizzle: phys = flat ^ (((flat>>5)&7)<<3)   [ushort units; 16B slot in 128B]
  const int swA = (tid >> 2) & 7;
  const int sa_w0 = (tid * 8) ^ (swA << 3);
  const int sa_w1 = ((tid + 256) * 8) ^ (swA << 3);
  const int sb_w = (brow * 32 + bhalf * 16) ^ ((brow & 7) << 3);

  int ptap = -1; size_t rowb = 0; bool bval = false;

  auto fetch = [&](int chunk, uint4 (&bg)[2][2], uint4& av0, uint4& av1) {
    const int tap = chunk >> 3, cg = chunk & 7;
    if (tap != ptap) {
      ptap = tap;
      int ky, kx, iy, ix;
      if (KIND == 0) {
        ky = tap >> 2; kx = tap & 3;
        iy = 2 * bu - 1 + ky; ix = 2 * bvc - 1 + kx;
        bval = ((unsigned)iy < 64u) && ((unsigned)ix < 64u);
        rowb = ((size_t)(bimg * 4096 + iy * 64 + ix)) << 8;
      } else {
        ky = tap / 3; kx = tap - ky * 3;
        iy = bu - 1 + ky; ix = bvc - 1 + kx;
        bval = ((unsigned)iy < 32u) && ((unsigned)ix < 32u);
        rowb = ((size_t)(bimg * 1024 + iy * 32 + ix)) << 8;
      }
    }
    const int koff = cg * 32 + bhalf * 16;
    if (bval) {
      bg[0][0] = *(const uint4*)(x0 + rowb + koff);
      bg[0][1] = *(const uint4*)(x0 + rowb + koff + 8);
      bg[1][0] = *(const uint4*)(x1 + rowb + koff);
      bg[1][1] = *(const uint4*)(x1 + rowb + koff + 8);
    } else {
      uint4 z; z.x = 0; z.y = 0; z.z = 0; z.w = 0;
      bg[0][0] = z; bg[0][1] = z; bg[1][0] = z; bg[1][1] = z;
    }
    const ushort_t* ap = wp + ((size_t)(chunk * 4 + coT) << 12);
    av0 = *(const uint4*)(ap + tid * 8);
    av1 = *(const uint4*)(ap + (tid + 256) * 8);
  };
  auto store = [&](ushort_t* buf, uint4 (&bg)[2][2], uint4& av0, uint4& av1) {
    *(uint4*)(buf + sa_w0) = av0;
    *(uint4*)(buf + sa_w1) = av1;
    ushort_t* sB = buf + 4096;
    *(uint4*)(sB + sb_w) = bg[0][0];
    *(uint4*)(sB + (sb_w ^ 8)) = bg[0][1];
    *(uint4*)(sB + 4096 + sb_w) = bg[1][0];
    *(uint4*)(sB + 4096 + (sb_w ^ 8)) = bg[1][1];
  };
  auto compute = [&](const ushort_t* buf) {
    const ushort_t* sA = buf;
    const ushort_t* sB = buf + 4096;
    short8 af[4][2], bf[2][2];
#pragma unroll
    for (int m = 0; m < 4; ++m) {
      const int row = m * 16 + l15;
      const int fb = row * 32 + q * 8;
      const int sw = (row & 7) << 3;
#pragma unroll
      for (int pl = 0; pl < 2; ++pl)
        af[m][pl] = *(const short8*)(sA + ((pl * 2048 + fb) ^ sw));
    }
#pragma unroll
    for (int n = 0; n < 2; ++n) {
      const int row = wv * 32 + n * 16 + l15;
      const int fb = row * 32 + q * 8;
      const int sw = (row & 7) << 3;
#pragma unroll
      for (int pl = 0; pl < 2; ++pl)
        bf[n][pl] = *(const short8*)(sB + ((pl * 4096 + fb) ^ sw));
    }
    __builtin_amdgcn_s_setprio(1);
#pragma unroll
    for (int m = 0; m < 4; ++m)
#pragma unroll
      for (int n = 0; n < 2; ++n) {
        acc[m][n] = __builtin_amdgcn_mfma_f32_16x16x32_bf16(af[m][0], bf[n][0], acc[m][n], 0, 0, 0);
        acc[m][n] = __builtin_amdgcn_mfma_f32_16x16x32_bf16(af[m][0], bf[n][1], acc[m][n], 0, 0, 0);
        acc[m][n] = __builtin_amdgcn_mfma_f32_16x16x32_bf16(af[m][1], bf[n][0], acc[m][n], 0, 0, 0);
      }
    __builtin_amdgcn_s_setprio(0);
  };

  uint4 bgP[2][2], avP0, avP1, bgQ[2][2], avQ0, avQ1;
  fetch(CH0, bgP, avP0, avP1);
  store(smem[0], bgP, avP0, avP1);   // waits only P's loads (counted)
  fetch(CH0 + 1, bgQ, avQ0, avQ1);   // in flight across barrier
  fence_lgkm_barrier();
  int cur = 0;
  for (int c = CH0; c < CH1; ++c) {
    compute(smem[cur]);
    if (c + 1 < CH1) {
      if (((c - CH0) & 1) == 0) {
        if (c + 2 < CH1) fetch(c + 2, bgP, avP0, avP1);  // issue before wait
        store(smem[cur ^ 1], bgQ, avQ0, avQ1);           // counted vmcnt (1 iter old)
      } else {
        if (c + 2 < CH1) fetch(c + 2, bgQ, avQ0, avQ1);
        store(smem[cur ^ 1], bgP, avP0, avP1);
      }
      fence_lgkm_barrier();   // no vmcnt drain: c+2 loads stay in flight
      cur ^= 1;
    }
  }

  // plain stores to this kz's private partial slice (deterministic)
  float* pz = part + ((size_t)blockIdx.z << 21);
#pragma unroll
  for (int m = 0; m < 4; ++m) {
#pragma unroll
    for (int n = 0; n < 2; ++n) {
#pragma unroll
      for (int r = 0; r < 4; ++r) {
        const int co_l = m * 16 + q * 4 + r;
        const int px_l = wv * 32 + n * 16 + l15;
        const int px = pxT * 128 + px_l;
        const int img = px >> 10, pp = px & 1023;
        const size_t ha = ((size_t)(img * 256 + coT * 64 + co_l)) * 1024 + pp;
        pz[ha] = acc[m][n][r];
      }
    }
  }
}

// ---------- epilogue for split convs ----------
// v = p0 + p1 + bias (fixed order -> deterministic).
// WH (conv2): v=relu(v); h32=v; split v.   !WH (3x3): split relu(v).
template<bool WH>
__global__ __launch_bounds__(256) void k_enc_epi(
    const float* __restrict__ part, float* __restrict__ h32,
    ushort_t* __restrict__ s0, ushort_t* __restrict__ s1,
    const float* __restrict__ bias)
{
  const int px = blockIdx.x * 256 + threadIdx.x;  // 8192
  const int co0 = blockIdx.y * 16;
  const int img = px >> 10, pp = px & 1023;
  const float* part1 = part + (1u << 21);
  uint p0[8], p1[8];
#pragma unroll
  for (int i = 0; i < 8; ++i) {
    size_t ha = ((size_t)(img * 256 + co0 + 2 * i)) * 1024 + pp;
    size_t hb = ha + 1024;
    float va = part[ha] + part1[ha] + bias[co0 + 2 * i];
    float vb = part[hb] + part1[hb] + bias[co0 + 2 * i + 1];
    float sa, sb;
    if (WH) {
      va = fmaxf(va, 0.f); vb = fmaxf(vb, 0.f);
      h32[ha] = va; h32[hb] = vb; sa = va; sb = vb;
    } else { sa = fmaxf(va, 0.f); sb = fmaxf(vb, 0.f); }
    ushort_t a0 = f2bf(sa), b0 = f2bf(sb);
    p0[i] = (uint)a0 | ((uint)b0 << 16);
    p1[i] = (uint)f2bf(sa - bf2f(a0)) | ((uint)f2bf(sb - bf2f(b0)) << 16);
  }
  ushort_t* d0 = s0 + (size_t)px * 256 + co0;
  ushort_t* d1 = s1 + (size_t)px * 256 + co0;
  uint4 v0a; v0a.x = p0[0]; v0a.y = p0[1]; v0a.z = p0[2]; v0a.w = p0[3];
  uint4 v0b; v0b.x = p0[4]; v0b.y = p0[5]; v0b.z = p0[6]; v0b.w = p0[7];
  uint4 v1a; v1a.x = p1[0]; v1a.y = p1[1]; v1a.z = p1[2]; v1a.w = p1[3];
  uint4 v1b; v1b.x = p1[4]; v1b.y = p1[5]; v1b.z = p1[6]; v1b.w = p1[7];
  *(uint4*)d0 = v0a; *(uint4*)(d0 + 8) = v0b;
  *(uint4*)d1 = v1a; *(uint4*)(d1 + 8) = v1b;
}

// ---------- encoder 1x1 MFMA (unsplit, fused epilogue) ----------
template<int KIND, bool ADD, bool RELUV, bool WH, bool WS>
__global__ __launch_bounds__(256) void k_enc_mfma(
    const ushort_t* __restrict__ x0, const ushort_t* __restrict__ x1,
    const ushort_t* __restrict__ wp, const float* __restrict__ bias,
    float* __restrict__ h32, ushort_t* __restrict__ sp0, ushort_t* __restrict__ sp1)
{
  __shared__ ushort_t smem[24576];   // dbuf 2x12288; epilogue reuses [0,18432)
  const int tid = threadIdx.x, lane = tid & 63, wv = tid >> 6;
  const int l15 = lane & 15, q = lane >> 4;
  const int pxT = blockIdx.x, coT = blockIdx.y;
  constexpr int NCH = (KIND == 0) ? 128 : (KIND == 1 ? 72 : 8);
  f32x4 acc[4][2];
#pragma unroll
  for (int m = 0; m < 4; ++m)
#pragma unroll
    for (int n = 0; n < 2; ++n) acc[m][n] = (f32x4){0.f, 0.f, 0.f, 0.f};

  const int brow = tid >> 1, bhalf = tid & 1;
  const int bpx = pxT * 128 + brow;
  const int bimg = bpx >> 10, bp = bpx & 1023, bu = bp >> 5, bvc = bp & 31;

  const int swA = (tid >> 2) & 7;
  const int sa_w0 = (tid * 8) ^ (swA << 3);
  const int sa_w1 = ((tid + 256) * 8) ^ (swA << 3);
  const int sb_w = (brow * 32 + bhalf * 16) ^ ((brow & 7) << 3);

  int ptap = -1; size_t rowb = 0; bool bval = (KIND == 2);
  if (KIND == 2) rowb = ((size_t)bpx) << 8;

  auto fetch = [&](int chunk, uint4 (&bg)[2][2], uint4& av0, uint4& av1) {
    const int tap = chunk >> 3, cg = chunk & 7;
    if (KIND != 2 && tap != ptap) {
      ptap = tap;
      int ky, kx, iy, ix;
      if (KIND == 0) {
        ky = tap >> 2; kx = tap & 3;
        iy = 2 * bu - 1 + ky; ix = 2 * bvc - 1 + kx;
        bval = ((unsigned)iy < 64u) && ((unsigned)ix < 64u);
        rowb = ((size_t)(bimg * 4096 + iy * 64 + ix)) << 8;
      } else {
        ky = tap / 3; kx = tap - ky * 3;
        iy = bu - 1 + ky; ix = bvc - 1 + kx;
        bval = ((unsigned)iy < 32u) && ((unsigned)ix < 32u);
        rowb = ((size_t)(bimg * 1024 + iy * 32 + ix)) << 8;
      }
    }
    const int koff = cg * 32 + bhalf * 16;
    if (bval) {
      bg[0][0] = *(const uint4*)(x0 + rowb + koff);
      bg[0][1] = *(const uint4*)(x0 + rowb + koff + 8);
      bg[1][0] = *(const uint4*)(x1 + rowb + koff);
      bg[1][1] = *(const uint4*)(x1 + rowb + koff + 8);
    } else {
      uint4 z; z.x = 0; z.y = 0; z.z = 0; z.w = 0;
      bg[0][0] = z; bg[0][1] = z; bg[1][0] = z; bg[1][1] = z;
    }
    const ushort_t* ap = wp + ((size_t)(chunk * 4 + coT) << 12);
    av0 = *(const uint4*)(ap + tid * 8);
    av1 = *(const uint4*)(ap + (tid + 256) * 8);
  };
  auto store = [&](ushort_t* buf, uint4 (&bg)[2][2], uint4& av0, uint4& av1) {
    *(uint4*)(buf + sa_w0) = av0;
    *(uint4*)(buf + sa_w1) = av1;
    ushort_t* sB = buf + 4096;
    *(uint4*)(sB + sb_w) = bg[0][0];
    *(uint4*)(sB + (sb_w ^ 8)) = bg[0][1];
    *(uint4*)(sB + 4096 + sb_w) = bg[1][0];
    *(uint4*)(sB + 4096 + (sb_w ^ 8)) = bg[1][1];
  };
  auto compute = [&](const ushort_t* buf) {
    const ushort_t* sA = buf;
    const ushort_t* sB = buf + 4096;
    short8 af[4][2], bf[2][2];
#pragma unroll
    for (int m = 0; m < 4; ++m) {
      const int row = m * 16 + l15;
      const int fb = row * 32 + q * 8;
      const int sw = (row & 7) << 3;
#pragma unroll
      for (int pl = 0; pl < 2; ++pl)
        af[m][pl] = *(const short8*)(sA + ((pl * 2048 + fb) ^ sw));
    }
#pragma unroll
    for (int n = 0; n < 2; ++n) {
      const int row = wv * 32 + n * 16 + l15;
      const int fb = row * 32 + q * 8;
      const int sw = (row & 7) << 3;
#pragma unroll
      for (int pl = 0; pl < 2; ++pl)
        bf[n][pl] = *(const short8*)(sB + ((pl * 4096 + fb) ^ sw));
    }
    __builtin_amdgcn_s_setprio(1);
#pragma unroll
    for (int m = 0; m < 4; ++m)
#pragma unroll
      for (int n = 0; n < 2; ++n) {
        acc[m][n] = __builtin_amdgcn_mfma_f32_16x16x32_bf16(af[m][0], bf[n][0], acc[m][n], 0, 0, 0);
        acc[m][n] = __builtin_amdgcn_mfma_f32_16x16x32_bf16(af[m][0], bf[n][1], acc[m][n], 0, 0, 0);
        acc[m][n] = __builtin_amdgcn_mfma_f32_16x16x32_bf16(af[m][1], bf[n][0], acc[m][n], 0, 0, 0);
      }
    __builtin_amdgcn_s_setprio(0);
  };

  uint4 bgP[2][2], avP0, avP1, bgQ[2][2], avQ0, avQ1;
  fetch(0, bgP, avP0, avP1);
  store(smem, bgP, avP0, avP1);
  fetch(1, bgQ, avQ0, avQ1);
  fence_lgkm_barrier();
  int cur = 0;
  for (int c = 0; c < NCH; ++c) {
    compute(smem + cur * 12288);
    if (c + 1 < NCH) {
      if ((c & 1) == 0) {
        if (c + 2 < NCH) fetch(c + 2, bgP, avP0, avP1);
        store(smem + (cur ^ 1) * 12288, bgQ, avQ0, avQ1);
      } else {
        if (c + 2 < NCH) fetch(c + 2, bgQ, avQ0, avQ1);
        store(smem + (cur ^ 1) * 12288, bgP, avP0, avP1);
      }
      fence_lgkm_barrier();
      cur ^= 1;
    }
  }

  __syncthreads();
#pragma unroll
  for (int m = 0; m < 4; ++m) {
#pragma unroll
    for (int n = 0; n < 2; ++n) {
#pragma unroll
      for (int r = 0; r < 4; ++r) {
        const int co_l = m * 16 + q * 4 + r;
        const int px_l = wv * 32 + n * 16 + l15;
        float v = acc[m][n][r] + bias[coT * 64 + co_l];
        const int px = pxT * 128 + px_l;
        const int img = px >> 10, pp = px & 1023;
        const size_t ha = ((size_t)(img * 256 + coT * 64 + co_l)) * 1024 + pp;
        if (ADD) v += h32[ha];
        if (RELUV) v = fmaxf(v, 0.f);
        if (WH) h32[ha] = v;
        if (WS) {
          float sv = fmaxf(v, 0.f);
          ushort_t b0 = f2bf(sv);
          smem[px_l * 72 + co_l] = b0;
          smem[9216 + px_l * 72 + co_l] = f2bf(sv - bf2f(b0));
        }
      }
    }
  }
  if (WS) {
    __syncthreads();
#pragma unroll
    for (int i = 0; i < 8; ++i) {
      int idx = tid + 256 * i;
      int pl = idx >> 10, w2 = idx & 1023, pxl = w2 >> 3, g = w2 & 7;
      uint4 vv = *(const uint4*)(smem + pl * 9216 + pxl * 72 + g * 8);
      ushort_t* dst = (pl ? sp1 : sp0) + ((size_t)(pxT * 128 + pxl)) * 256 + coT * 64 + g * 8;
      *(uint4*)dst = vv;
    }
  }
}

// ---------- 1x1 conv fp32 (to_z only) ----------
__global__ __launch_bounds__(256) void k_conv1x1(
    const float* __restrict__ in, float* __restrict__ out,
    const float* __restrict__ wT, const float* __restrict__ bias,
    int CI, int CO, int P)
{
  const int p = blockIdx.x * 256 + threadIdx.x;
  const int cob = blockIdx.y * 16;
  const int n = blockIdx.z;
  const float* inN = in + (size_t)n * CI * P + p;
  float acc[16];
#pragma unroll
  for (int i = 0; i < 16; ++i) acc[i] = bias[cob + i];
  const float* wr = wT + cob;
#pragma unroll 4
  for (int ci = 0; ci < CI; ++ci) {
    float iv = inN[(size_t)ci * P];
    const float* w = wr + (size_t)ci * CO;  // uniform
#pragma unroll
    for (int i = 0; i < 16; ++i) acc[i] = fmaf(iv, w[i], acc[i]);
  }
  float* outN = out + (size_t)n * CO * P + p;
#pragma unroll
  for (int i = 0; i < 16; ++i) outN[(size_t)(cob + i) * P] = acc[i];
}

// ---------- VQ partial: 16 chunks of 32 codes; per-j math identical ----------
__global__ __launch_bounds__(256) void k_vq_part(
    const float* __restrict__ z_e, const float* __restrict__ cb,
    const float* __restrict__ cnorm, float* __restrict__ pbest, int* __restrict__ pbid)
{
  int g = blockIdx.x * 256 + threadIdx.x;  // 8192 points
  int chunk = blockIdx.y;                  // 16 chunks
  int img = g >> 10, p = g & 1023;
  const float* zp = z_e + (size_t)img * 64 * 1024 + p;
  float z[64];
#pragma unroll
  for (int c = 0; c < 64; ++c) z[c] = zp[(size_t)c * 1024];
  float best = 3.4e38f; int bid = chunk << 5;
  const int j0 = chunk << 5;
  for (int j = j0; j < j0 + 32; ++j) {
    const float* cj = cb + j * 64;  // uniform -> scalar loads
    float m = 0.f;
#pragma unroll
    for (int c = 0; c < 64; ++c) m = fmaf(z[c], cj[c], m);
    float d = fmaf(-2.f, m, cnorm[j]);
    if (d < best) { best = d; bid = j; }  // strict <: first-min within chunk
  }
  pbest[chunk * 8192 + g] = best;
  pbid[chunk * 8192 + g] = bid;
}

// ---------- VQ reduce: argmin across chunks (ascending -> np.argmin) + e_k ----------
__global__ __launch_bounds__(256) void k_vq_reduce(
    const float* __restrict__ pbest, const int* __restrict__ pbid,
    const float* __restrict__ cb, float* __restrict__ ids_f, float* __restrict__ ek)
{
  int g = blockIdx.x * 256 + threadIdx.x;  // 8192
  float best = 3.4e38f; int bid = 0;
#pragma unroll
  for (int ch = 0; ch < 16; ++ch) {
    float d = pbest[ch * 8192 + g];
    int b = pbid[ch * 8192 + g];
    if (d < best) { best = d; bid = b; }
  }
  ids_f[g] = (float)bid;
  int img = g >> 10, p = g & 1023;
  const float* cbid = cb + bid * 64;
  float* ekp = ek + (size_t)img * 64 * 1024 + p;
#pragma unroll
  for (int c = 0; c < 64; ++c) ekp[(size_t)c * 1024] = cbid[c];
}

// ---------- from_z 1x1 (64->256) + relu -> NHWC bf16 ----------
__global__ __launch_bounds__(256) void k_from_z(
    const float* __restrict__ ek, ushort_t* __restrict__ nhwc,
    const float* __restrict__ wT, const float* __restrict__ bias)
{
  const int p = blockIdx.x * 256 + threadIdx.x;  // 0..1023
  const int co0 = blockIdx.y * 16;
  const int n = blockIdx.z;
  const float* inN = ek + (size_t)n * 64 * 1024 + p;
  float acc[16];
#pragma unroll
  for (int i = 0; i < 16; ++i) acc[i] = bias[co0 + i];
#pragma unroll 4
  for (int ci = 0; ci < 64; ++ci) {
    float iv = inN[(size_t)ci * 1024];
    const float* w = wT + (size_t)ci * 256 + co0;  // uniform
#pragma unroll
    for (int i = 0; i < 16; ++i) acc[i] = fmaf(iv, w[i], acc[i]);
  }
  uint pk[8];
#pragma unroll
  for (int i = 0; i < 8; ++i) {
    ushort_t lo = f2bf(fmaxf(acc[2 * i], 0.f));
    ushort_t hi = f2bf(fmaxf(acc[2 * i + 1], 0.f));
    pk[i] = (uint)lo | ((uint)hi << 16);
  }
  ushort_t* op = nhwc + (((size_t)n * 1024 + p) * 256 + co0);
  uint4 v0; v0.x = pk[0]; v0.y = pk[1]; v0.z = pk[2]; v0.w = pk[3];
  uint4 v1; v1.x = pk[4]; v1.y = pk[5]; v1.z = pk[6]; v1.w = pk[7];
  *(uint4*)(op) = v0;
  *(uint4*)(op + 8) = v1;
}

// ---------- t1 convtranspose 4x4 s2 p1, 256->256, bf16 MFMA, relu -> bf16 NHWC
// R4: 2-deep P/Q prefetch + raw barrier (counted vmcnt), swizzle kept.
__global__ __launch_bounds__(256) void k_mfma_t1(
    const ushort_t* __restrict__ nhwc, const ushort_t* __restrict__ wb,
    const float* __restrict__ bias, ushort_t* __restrict__ t1o)
{
  __shared__ ushort_t smem[2][8192];   // per buf: sA 4096 | sB 4096
  const int tid = threadIdx.x;
  const int lane = tid & 63;
  const int wv = tid >> 6;
  const int wm = wv & 1, wn = wv >> 1;
  const int l15 = lane & 15, q = lane >> 4;
  const int pxT = blockIdx.x, coT = blockIdx.y, par = blockIdx.z;
  const int ry = par & 1, rx = (par >> 1) & 1;
  const int pxbase = pxT * 128;
  const int img = pxbase >> 10;
  f32x4 acc[4][4];
#pragma unroll
  for (int i = 0; i < 4; ++i)
#pragma unroll
    for (int j = 0; j < 4; ++j) acc[i][j] = (f32x4){0.f, 0.f, 0.f, 0.f};

  const int srow = tid >> 2, kg = tid & 3;
  const int ssw = (srow & 7) << 3;                     // (srow+64)&7 == srow&7
  const int sw0 = (srow * 32 + kg * 8) ^ ssw;
  const int sw1 = ((srow + 64) * 32 + kg * 8) ^ ssw;

  auto fetch = [&](int c, uint4& a0, uint4& a1, uint4& b0, uint4& b1) {
    const int tap = c >> 3, c8 = c & 7;
    const int ta = tap >> 1, tb = tap & 1;
    const ushort_t* Abase = wb + ((size_t)((par * 4 + tap) * 8 + c8) << 13);
    a0 = *(const uint4*)(Abase + (coT * 128 + srow) * 32 + kg * 8);
    a1 = *(const uint4*)(Abase + (coT * 128 + srow + 64) * 32 + kg * 8);
#pragma unroll
    for (int r = 0; r < 2; ++r) {
      const int row = srow + 64 * r;
      const int px = pxbase + row;
      const int u = (px >> 5) & 31, vv = px & 31;
      const int iy = u + ry - ta, ix = vv + rx - tb;
      uint4 val;
      if ((unsigned)iy < 32u && (unsigned)ix < 32u)
        val = *(const uint4*)(nhwc + ((size_t)(img * 1024 + iy * 32 + ix) * 256 + c8 * 32 + kg * 8));
      else { val.x = 0u; val.y = 0u; val.z = 0u; val.w = 0u; }
      if (r == 0) b0 = val; else b1 = val;
    }
  };
  auto store = [&](ushort_t* buf, uint4& a0, uint4& a1, uint4& b0, uint4& b1) {
    *(uint4*)(buf + sw0) = a0;
    *(uint4*)(buf + sw1) = a1;
    *(uint4*)(buf + 4096 + sw0) = b0;
    *(uint4*)(buf + 4096 + sw1) = b1;
  };
  auto compute = [&](const ushort_t* buf) {
    const ushort_t* sA = buf;
    const ushort_t* sB = buf + 4096;
    short8 af[4], bfr[4];
#pragma unroll
    for (int i = 0; i < 4; ++i) {
      const int row = wm * 64 + i * 16 + l15;
      af[i] = *(const short8*)(sA + ((row * 32 + q * 8) ^ ((row & 7) << 3)));
    }
#pragma unroll
    for (int j = 0; j < 4; ++j) {
      const int row = wn * 64 + j * 16 + l15;
      bfr[j] = *(const short8*)(sB + ((row * 32 + q * 8) ^ ((row & 7) << 3)));
    }
    __builtin_amdgcn_s_setprio(1);
#pragma unroll
    for (int i = 0; i < 4; ++i)
#pragma unroll
      for (int j = 0; j < 4; ++j)
        acc[i][j] = __builtin_amdgcn_mfma_f32_16x16x32_bf16(af[i], bfr[j], acc[i][j], 0, 0, 0);
    __builtin_amdgcn_s_setprio(0);
  };

  uint4 aP0, aP1, bP0, bP1, aQ0, aQ1, bQ0, bQ1;
  fetch(0, aP0, aP1, bP0, bP1);
  store(smem[0], aP0, aP1, bP0, bP1);
  fetch(1, aQ0, aQ1, bQ0, bQ1);
  fence_lgkm_barrier();
  int cur = 0;
  for (int c = 0; c < 32; ++c) {
    compute(smem[cur]);
    if (c + 1 < 32) {
      if ((c & 1) == 0) {
        if (c + 2 < 32) fetch(c + 2, aP0, aP1, bP0, bP1);
        store(smem[cur ^ 1], aQ0, aQ1, bQ0, bQ1);
      } else {
        if (c + 2 < 32) fetch(c + 2, aQ0, aQ1, bQ0, bQ1);
        store(smem[cur ^ 1], aP0, aP1, bP0, bP1);
      }
      fence_lgkm_barrier();
      cur ^= 1;
    }
  }

#pragma unroll
  for (int i = 0; i < 4; ++i) {
    int co = coT * 128 + wm * 64 + i * 16 + q * 4;
#pragma unroll
    for (int j = 0; j < 4; ++j) {
      int px = pxbase + wn * 64 + j * 16 + l15;
      int u = (px >> 5) & 31, vv = px & 31;
      int oy = 2 * u + ry, ox = 2 * vv + rx;
      ushort_t e0 = f2bf(fmaxf(acc[i][j][0] + bias[co + 0], 0.f));
      ushort_t e1 = f2bf(fmaxf(acc[i][j][1] + bias[co + 1], 0.f));
      ushort_t e2 = f2bf(fmaxf(acc[i][j][2] + bias[co + 2], 0.f));
      ushort_t e3 = f2bf(fmaxf(acc[i][j][3] + bias[co + 3], 0.f));
      uint2 pk; pk.x = (uint)e0 | ((uint)e1 << 16); pk.y = (uint)e2 | ((uint)e3 << 16);
      *(uint2*)(t1o + ((size_t)(img * 4096 + oy * 64 + ox) * 256 + co)) = pk;
    }
  }
}

// ---------- t2 convtranspose 4x4 s2 p1, 256->3, bf16 MFMA, sigmoid ----------
__global__ __launch_bounds__(256) void k_mfma_t2(
    const ushort_t* __restrict__ t1o, const ushort_t* __restrict__ wb,
    const float* __restrict__ bias, float* __restrict__ out)
{
  __shared__ ushort_t sA2[256 * 32];
  __shared__ ushort_t sB2[16 * 32];
  const int tid = threadIdx.x, lane = tid & 63, wv = tid >> 6;
  const int l15 = lane & 15, q = lane >> 4;
  const int pxb = blockIdx.x * 256;
  const int par = blockIdx.y;
  const int ry = par & 1, rx = (par >> 1) & 1;
  f32x4 acc[4];
#pragma unroll
  for (int m = 0; m < 4; ++m) acc[m] = (f32x4){0.f, 0.f, 0.f, 0.f};
  const int kg = tid & 3;
  const int ssw = ((tid >> 2) & 7) << 3;
  size_t rb[4]; bool rv[4];
  for (int chunk = 0; chunk < 32; ++chunk) {
    const int tap = chunk >> 3, cg = chunk & 7;
    const int a = tap >> 1, b = tap & 1;
    if ((chunk & 7) == 0) {
#pragma unroll
      for (int i = 0; i < 4; ++i) {
        int row = (tid >> 2) + 64 * i;
        int px = pxb + row;
        int img = px >> 12, p = px & 4095, u = p >> 6, v = p & 63;
        int iy = u + ry - a, ix = v + rx - b;
        rv[i] = ((unsigned)iy < 64u) && ((unsigned)ix < 64u);
        rb[i] = ((size_t)(img * 4096 + iy * 64 + ix)) << 8;
      }
    }
    uint4 av[4];
#pragma unroll
    for (int i = 0; i < 4; ++i) {
      if (rv[i]) av[i] = *(const uint4*)(t1o + rb[i] + cg * 32 + kg * 8);
      else { av[i].x = 0; av[i].y = 0; av[i].z = 0; av[i].w = 0; }
    }
    uint4 bv;
    if (tid < 64) bv = *(const uint4*)(wb + ((size_t)(par * 32 + chunk)) * 512 + tid * 8);
    __syncthreads();
#pragma unroll
    for (int i = 0; i < 4; ++i)
      *(uint4*)(sA2 + (((((tid >> 2) + 64 * i) * 32) + kg * 8) ^ ssw)) = av[i];
    if (tid < 64) *(uint4*)(sB2 + ((tid * 8) ^ ssw)) = bv;
    __syncthreads();
    short8 bf = *(const short8*)(sB2 + ((l15 * 32 + q * 8) ^ ((l15 & 7) << 3)));
#pragma unroll
    for (int m = 0; m < 4; ++m) {
      const int row = wv * 64 + m * 16 + l15;
      short8 af = *(const short8*)(sA2 + ((row * 32 + q * 8) ^ ((row & 7) << 3)));
      acc[m] = __builtin_amdgcn_mfma_f32_16x16x32_bf16(af, bf, acc[m], 0, 0, 0);
    }
    __syncthreads();
  }
  const int co = l15;
  if (co < 3) {
    float bco = bias[co];
#pragma unroll
    for (int m = 0; m < 4; ++m) {
#pragma unroll
      for (int r = 0; r < 4; ++r) {
        int px = pxb + wv * 64 + m * 16 + q * 4 + r;
        int img = px >> 12, p = px & 4095, u = p >> 6, v = p & 63;
        size_t addr = ((size_t)(img * 3 + co)) * 16384 + (2 * u + ry) * 128 + (2 * v + rx);
        out[addr] = 1.f / (1.f + expf(-(acc[m][r] + bco)));
      }
    }
  }
}

// ---------------------------------------------------------------------------
extern "C" void kernel_launch(void* const* d_in, const int* in_sizes, int n_in,
                              void* d_out, int out_size, void* d_ws, size_t ws_size,
                              hipStream_t stream) {
  (void)in_sizes; (void)n_in; (void)out_size; (void)ws_size;
  const float* x      = (const float*)d_in[0];
  const float* c1_w   = (const float*)d_in[1];
  const float* c1_b   = (const float*)d_in[2];
  const float* c2_w   = (const float*)d_in[3];
  const float* c2_b   = (const float*)d_in[4];
  const float* r0_w3  = (const float*)d_in[5];
  const float* r0_b3  = (const float*)d_in[6];
  const float* r0_w1  = (const float*)d_in[7];
  const float* r0_b1  = (const float*)d_in[8];
  const float* r1_w3  = (const float*)d_in[9];
  const float* r1_b3  = (const float*)d_in[10];
  const float* r1_w1  = (const float*)d_in[11];
  const float* r1_b1  = (const float*)d_in[12];
  const float* to_z_w = (const float*)d_in[13];
  const float* to_z_b = (const float*)d_in[14];
  const float* cb     = (const float*)d_in[15];
  const float* from_z_w = (const float*)d_in[16];
  const float* from_z_b = (const float*)d_in[17];
  const float* t1_w   = (const float*)d_in[18];
  const float* t1_b   = (const float*)d_in[19];
  const float* t2_w   = (const float*)d_in[20];
  const float* t2_b   = (const float*)d_in[21];

  float* wsf = (float*)d_ws;
  // Era-choreographed regions (float offsets) — see R3 comments; unchanged.
  ushort_t* xs1p0 = (ushort_t*)(wsf + 0);
  ushort_t* xs1p1 = (ushort_t*)(wsf + 4194304);
  float*    cp0   = wsf + 8388608;               // conv2 partial kz0 (= h32 slot)
  float*    h32   = wsf + 8388608;
  float*    qp0   = wsf + 4194304;               // 3x3 partials (xs1p1 slot, dead)
  ushort_t* sE0   = (ushort_t*)(wsf + 0);        // split ping [0,1.05M)
  ushort_t* sE1   = (ushort_t*)(wsf + 1048576);  // split ping [1.05,2.1M)
  ushort_t* sF0   = (ushort_t*)(wsf + 2097152);  // split pong [2.1,3.15M)
  ushort_t* sF1   = (ushort_t*)(wsf + 3145728);  // split pong [3.15,4.19M)
  float*    pbest = wsf + 0;                     // vq-era
  int*      pbid  = (int*)(wsf + 131072);        // vq-era
  ushort_t* t1out = (ushort_t*)(wsf + 2097152);  // dec-era [2.1M, 6.29M)
  ushort_t* decn  = (ushort_t*)(wsf + 6291456);  // dec-era [6.29M, 7.34M)
  ushort_t* wp_c2   = (ushort_t*)(wsf + 12582912);
  ushort_t* wp_r0w3 = (ushort_t*)(wsf + 13631488);
  ushort_t* wp_r1w3 = (ushort_t*)(wsf + 14221312);
  ushort_t* wp_r0w1 = (ushort_t*)(wsf + 14811136);
  ushort_t* wp_r1w1 = (ushort_t*)(wsf + 14876672);
  float*    wt_c1   = wsf + 14942208;
  float*    wt_toz  = wsf + 14954496;
  float*    wt_fromz= wsf + 14970880;
  ushort_t* t1wb    = (ushort_t*)(wsf + 14987264);
  ushort_t* w2pk    = (ushort_t*)(wsf + 15511552);
  float*    cnorm   = wsf + 15544320;

  float* out_img = (float*)d_out;        // 393216
  float* z_e_out = out_img + 393216;     // 524288
  float* e_k_out = z_e_out + 524288;     // 524288
  float* ids_out = e_k_out + 524288;     // 8192 (stored as float)

  // ---- weight prep ----
  k_transpose_w<<<48, 256, 0, stream>>>(c1_w, wt_c1, 256, 48);
  k_transpose_w<<<64, 256, 0, stream>>>(to_z_w, wt_toz, 64, 256);
  k_transpose_w<<<64, 256, 0, stream>>>(from_z_w, wt_fromz, 256, 64);
  k_prep_enc<0><<<8192, 256, 0, stream>>>(c2_w,  wp_c2,   128 << 14);
  k_prep_enc<1><<<4608, 256, 0, stream>>>(r0_w3, wp_r0w3, 72 << 14);
  k_prep_enc<1><<<4608, 256, 0, stream>>>(r1_w3, wp_r1w3, 72 << 14);
  k_prep_enc<2><<<512,  256, 0, stream>>>(r0_w1, wp_r0w1, 8 << 14);
  k_prep_enc<2><<<512,  256, 0, stream>>>(r1_w1, wp_r1w1, 8 << 14);
  k_prep_t1w<<<4096, 256, 0, stream>>>(t1_w, t1wb);
  k_prep_t2w<<<256, 256, 0, stream>>>(t2_w, w2pk);
  k_prep_cb<<<2, 256, 0, stream>>>(cb, cnorm);

  // ---- encoder ----
  k_conv1_split<<<dim3(64, 4, 8), 256, 0, stream>>>(x, xs1p0, xs1p1, wt_c1, c1_b);
  // conv2: plain-store partials cp0/cp1, epilogue: sum+relu -> h32 + splits
  k_enc_mfma_split<0><<<dim3(64, 4, 2), 256, 0, stream>>>(xs1p0, xs1p1, wp_c2, cp0);
  k_enc_epi<true><<<dim3(32, 16), 256, 0, stream>>>(cp0, h32, sE0, sE1, c2_b);
  // r0 w3
  k_enc_mfma_split<1><<<dim3(64, 4, 2), 256, 0, stream>>>(sE0, sE1, wp_r0w3, qp0);
  k_enc_epi<false><<<dim3(32, 16), 256, 0, stream>>>(qp0, nullptr, sE0, sE1, r0_b3);
  // r0 w1: h += conv; write h32 + split(relu(h))
  k_enc_mfma<2, true,  false, true,  true ><<<dim3(64, 4), 256, 0, stream>>>(
      sE0, sE1, wp_r0w1, r0_b1, h32, sF0, sF1);
  // r1 w3
  k_enc_mfma_split<1><<<dim3(64, 4, 2), 256, 0, stream>>>(sF0, sF1, wp_r1w3, qp0);
  k_enc_epi<false><<<dim3(32, 16), 256, 0, stream>>>(qp0, nullptr, sE0, sE1, r1_b3);
  // r1 w1: h += conv; write h32 only
  k_enc_mfma<2, true,  false, true,  false><<<dim3(64, 4), 256, 0, stream>>>(
      sE0, sE1, wp_r1w1, r1_b1, h32, nullptr, nullptr);
  // to_z (fp32)
  k_conv1x1<<<dim3(4, 4, 8), 256, 0, stream>>>(h32, z_e_out, wt_toz, to_z_b, 256, 64, 1024);

  // ---- VQ (chunk-parallel; bit-identical argmin) ----
  k_vq_part<<<dim3(32, 16), 256, 0, stream>>>(z_e_out, cb, cnorm, pbest, pbid);
  k_vq_reduce<<<32, 256, 0, stream>>>(pbest, pbid, cb, ids_out, e_k_out);

  // ---- decoder (bf16) ----
  k_from_z<<<dim3(4, 16, 8), 256, 0, stream>>>(e_k_out, decn, wt_fromz, from_z_b);
  k_mfma_t1<<<dim3(64, 2, 4), 256, 0, stream>>>(decn, t1wb, t1_b, t1out);
  k_mfma_t2<<<dim3(128, 4), 256, 0, stream>>>(t1out, w2pk, t2_b, out_img);
}

// Round 5
// 433.937 us; speedup vs baseline: 1.2268x; 1.2268x over previous
//
#include <hip/hip_runtime.h>
#include <math.h>

// ---------------------------------------------------------------------------
// VQ-VAE forward.
// Encoder: 256-ch convs as implicit-GEMM MFMA with 2-term bf16 split inputs
// (3 passes: w1x1 + w1x2 + w2x1). Big convs split-K=2 with PLAIN-STORE
// per-kz partial buffers (no atomics, no memset). VQ: chunk-parallel partial
// argmin + reduce. Decoder: t1 + t2.
// R5: staging via __builtin_amdgcn_global_load_lds width=16 (direct L2->LDS
//     DMA, no VGPR roundtrip, no ds_writes) with LINEAR LDS layout (the XOR
//     swizzle was measured a no-op: b128 reads are already bank-balanced).
//     Sync structure = R3's proven 1-barrier-per-chunk dbuf. No setprio, no
//     hand fences (R4 regression). Halo rows read a zero __device__ pad.
// ---------------------------------------------------------------------------

typedef unsigned int uint;
typedef unsigned short ushort_t;
using short8 = __attribute__((ext_vector_type(8))) short;
using f32x4  = __attribute__((ext_vector_type(4))) float;

// zero-initialized pad: invalid halo rows DMA from here (always zero)
__device__ __attribute__((aligned(16))) ushort_t g_zpad[512];

static __device__ __forceinline__ int rfl(int x) { return __builtin_amdgcn_readfirstlane(x); }
static __device__ __forceinline__ ushort_t f2bf(float f) {
  uint u = __float_as_uint(f);
  return (ushort_t)((u + 0x7fffu + ((u >> 16) & 1u)) >> 16);  // RNE; finite inputs
}
static __device__ __forceinline__ float bf2f(ushort_t b) {
  return __uint_as_float(((uint)b) << 16);
}
// direct global->LDS DMA, 16B per lane; lds dest = wave-uniform base + lane*16
static __device__ __forceinline__ void gload16(const ushort_t* g, void* l) {
  __builtin_amdgcn_global_load_lds(
      (const __attribute__((address_space(1))) void*)g,
      (__attribute__((address_space(3))) void*)l, 16, 0, 0);
}

// ---------- weight prep ----------
__global__ void k_transpose_w(const float* __restrict__ w, float* __restrict__ wT, int CO, int CIKK) {
  int idx = blockIdx.x * 256 + threadIdx.x;
  if (idx >= CO * CIKK) return;
  int co = idx % CO, i = idx / CO;
  wT[idx] = w[co * CIKK + i];
}

// encoder MFMA weight pack: w[co][ci(256)][KH][KW] fp32 ->
// wp[chunk][coT(4)][pl(2)][row(64)][k(32)] bf16 split, chunk = tap*8 + cg
template<int KIND>  // 0: 4x4 (16 taps), 1: 3x3 (9 taps), 2: 1x1 (1 tap)
__global__ void k_prep_enc(const float* __restrict__ w, ushort_t* __restrict__ wp, int total) {
  int idx = blockIdx.x * 256 + threadIdx.x;
  if (idx >= total) return;
  int k = idx & 31, row = (idx >> 5) & 63, pl = (idx >> 11) & 1, coT = (idx >> 12) & 3, chunk = idx >> 14;
  int tap = chunk >> 3, cg = chunk & 7;
  int co = coT * 64 + row, ci = cg * 32 + k;
  int ky, kx, KK, KW;
  if (KIND == 0)      { ky = tap >> 2; kx = tap & 3;       KK = 16; KW = 4; }
  else if (KIND == 1) { ky = tap / 3;  kx = tap - ky * 3;  KK = 9;  KW = 3; }
  else                { ky = 0;        kx = 0;             KK = 1;  KW = 1; }
  float v = w[(co * 256 + ci) * KK + ky * KW + kx];
  ushort_t b0 = f2bf(v);
  wp[idx] = pl ? f2bf(v - bf2f(b0)) : b0;
}

// t1_w [ci][co][ky][kx] -> bf16 [par][tap][c8][co][kk32]
__global__ void k_prep_t1w(const float* __restrict__ w, ushort_t* __restrict__ wb) {
  int idx = blockIdx.x * 256 + threadIdx.x;  // 1048576
  int kk  = idx & 31;
  int co  = (idx >> 5) & 255;
  int c8  = (idx >> 13) & 7;
  int tap = (idx >> 16) & 3;
  int par = idx >> 18;
  int ry = par & 1, rx = (par >> 1) & 1;
  int a = tap >> 1, b = tap & 1;
  int ky = ((ry + 1) & 1) + 2 * a;
  int kx = ((rx + 1) & 1) + 2 * b;
  int ci = c8 * 32 + kk;
  wb[idx] = f2bf(w[((ci * 256 + co) << 4) + ky * 4 + kx]);
}

// t2_w [ci(256)][co(3)][4][4] -> bf16 [par(4)][chunk(32)][co16][k32]
__global__ void k_prep_t2w(const float* __restrict__ w, ushort_t* __restrict__ wb) {
  int idx = blockIdx.x * 256 + threadIdx.x;  // 65536
  int k = idx & 31, co = (idx >> 5) & 15, chunk = (idx >> 9) & 31, par = idx >> 14;
  int tap = chunk >> 3, cg = chunk & 7;
  int a = tap >> 1, b = tap & 1;
  int ry = par & 1, rx = (par >> 1) & 1;
  int ky = ((ry + 1) & 1) + 2 * a;
  int kx = ((rx + 1) & 1) + 2 * b;
  int ci = cg * 32 + k;
  float v = (co < 3) ? w[((ci * 3 + co) << 4) + ky * 4 + kx] : 0.f;
  wb[idx] = f2bf(v);
}

// cnorm[j] = sum_c cb[j][c]^2
__global__ void k_prep_cb(const float* __restrict__ cb, float* __restrict__ cnorm) {
  int idx = blockIdx.x * 256 + threadIdx.x;
  if (idx < 512) {
    float s = 0.f;
    for (int c = 0; c < 64; ++c) { float v = cb[idx * 64 + c]; s = fmaf(v, v, s); }
    cnorm[idx] = s;
  }
}

// ---------- conv1: 3->256, 4x4 s2 p1, relu, output split-bf16 NHWC ----------
__global__ __launch_bounds__(256) void k_conv1_split(
    const float* __restrict__ in, ushort_t* __restrict__ o0, ushort_t* __restrict__ o1,
    const float* __restrict__ wT, const float* __restrict__ bias)
{
  __shared__ float s_in[3 * 360];  // parity-split cols, pitch 20 (2-way free)
  const int tid = threadIdx.x;
  const int lane = tid & 63;
  const int wv = rfl(tid >> 6);
  const int px = lane & 7, py = lane >> 3;
  const int tx = blockIdx.x & 7, ty = blockIdx.x >> 3;
  const int X = tx * 8, Y = ty * 8;
  const int cob = blockIdx.y * 64 + wv * 16;
  const int n = blockIdx.z;
  float acc[16];
#pragma unroll
  for (int i = 0; i < 16; ++i) acc[i] = bias[cob + i];
  const float* inN = in + (size_t)n * 3 * 16384;
  for (int e = tid; e < 3 * 360; e += 256) {
    int col2 = e % 20; int t = e / 20; int row = t % 18; int ci = t / 18;
    int pr = col2 / 10, hc = col2 % 10, ixl = 2 * hc + pr;
    int iy = 2 * Y - 1 + row, ix = 2 * X - 1 + ixl;
    float v = 0.f;
    if (ixl < 18 && (unsigned)iy < 128u && (unsigned)ix < 128u)
      v = inN[ci * 16384 + iy * 128 + ix];
    s_in[e] = v;
  }
  __syncthreads();
  const float* wc = wT + cob;
#pragma unroll
  for (int c = 0; c < 3; ++c) {
    const float* base = s_in + c * 360 + py * 40 + px;
#pragma unroll
    for (int ky = 0; ky < 4; ++ky) {
#pragma unroll
      for (int kx = 0; kx < 4; ++kx) {
        float iv = base[ky * 20 + (kx & 1) * 10 + (kx >> 1)];
        const float* w = wc + (size_t)(c * 16 + ky * 4 + kx) * 256;  // uniform
#pragma unroll
        for (int i = 0; i < 16; ++i) acc[i] = fmaf(iv, w[i], acc[i]);
      }
    }
  }
  const int pxg = n * 4096 + (Y + py) * 64 + (X + px);
  uint p0[8], p1[8];
#pragma unroll
  for (int i = 0; i < 8; ++i) {
    float va = fmaxf(acc[2 * i], 0.f), vb = fmaxf(acc[2 * i + 1], 0.f);
    ushort_t a0 = f2bf(va), b0 = f2bf(vb);
    ushort_t a1 = f2bf(va - bf2f(a0)), b1 = f2bf(vb - bf2f(b0));
    p0[i] = (uint)a0 | ((uint)b0 << 16);
    p1[i] = (uint)a1 | ((uint)b1 << 16);
  }
  ushort_t* d0 = o0 + (size_t)pxg * 256 + cob;
  ushort_t* d1 = o1 + (size_t)pxg * 256 + cob;
  uint4 v0a; v0a.x = p0[0]; v0a.y = p0[1]; v0a.z = p0[2]; v0a.w = p0[3];
  uint4 v0b; v0b.x = p0[4]; v0b.y = p0[5]; v0b.z = p0[6]; v0b.w = p0[7];
  uint4 v1a; v1a.x = p1[0]; v1a.y = p1[1]; v1a.z = p1[2]; v1a.w = p1[3];
  uint4 v1b; v1b.x = p1[4]; v1b.y = p1[5]; v1b.z = p1[6]; v1b.w = p1[7];
  *(uint4*)d0 = v0a; *(uint4*)(d0 + 8) = v0b;
  *(uint4*)d1 = v1a; *(uint4*)(d1 + 8) = v1b;
}

// ---------- encoder implicit-GEMM MFMA, split-K=2, plain-store partial ------
// Block: 64co x 128px, 4 waves; wave: 64co x 32px = 4x2 of 16x16x32; 3 passes.
// grid (pxT 64, coT 4, kz 2); kz block z stores its partial at part + z*2^21.
// R5: global_load_lds staging, linear LDS [sA: pl|row64|k32][sB: pl|row128|k32].
template<int KIND>  // 0: conv2 (128 chunks), 1: 3x3 (72 chunks)
__global__ __launch_bounds__(256) void k_enc_mfma_split(
    const ushort_t* __restrict__ x0, const ushort_t* __restrict__ x1,
    const ushort_t* __restrict__ wp, float* __restrict__ part)
{
  __shared__ ushort_t smem[2][12288];   // per buf: sA 4096 us (8KB) | sB 8192 us (16KB)
  const int tid = threadIdx.x, lane = tid & 63, wv = tid >> 6;
  const int l15 = lane & 15, q = lane >> 4;
  const int pxT = blockIdx.x, coT = blockIdx.y;
  constexpr int NCH = (KIND == 0) ? 128 : 72;
  const int CH0 = blockIdx.z * (NCH / 2), CH1 = CH0 + NCH / 2;
  f32x4 acc[4][2];
#pragma unroll
  for (int m = 0; m < 4; ++m)
#pragma unroll
    for (int n = 0; n < 2; ++n) acc[m][n] = (f32x4){0.f, 0.f, 0.f, 0.f};

  // B staging: thread handles rows r0 and r0+64, 16B quarter kq
  const int r0 = tid >> 2, kq = tid & 3;
  int bimg[2], bu[2], bvc[2];
#pragma unroll
  for (int r = 0; r < 2; ++r) {
    int bpx = pxT * 128 + r0 + r * 64;
    bimg[r] = bpx >> 10; int bp = bpx & 1023; bu[r] = bp >> 5; bvc[r] = bp & 31;
  }
  const ushort_t* srcB[2][2];  // [row r][plane p], excludes cg offset
  int ptap = -1;
  auto retap = [&](int tap) {
    ptap = tap;
    int ky, kx;
    if (KIND == 0) { ky = tap >> 2; kx = tap & 3; }
    else           { ky = tap / 3;  kx = tap - ky * 3; }
#pragma unroll
    for (int r = 0; r < 2; ++r) {
      bool v; size_t rowb;
      if (KIND == 0) {
        int iy = 2 * bu[r] - 1 + ky, ix = 2 * bvc[r] - 1 + kx;
        v = ((unsigned)iy < 64u) && ((unsigned)ix < 64u);
        rowb = ((size_t)(bimg[r] * 4096 + iy * 64 + ix)) << 8;
      } else {
        int iy = bu[r] - 1 + ky, ix = bvc[r] - 1 + kx;
        v = ((unsigned)iy < 32u) && ((unsigned)ix < 32u);
        rowb = ((size_t)(bimg[r] * 1024 + iy * 32 + ix)) << 8;
      }
      srcB[r][0] = (v ? (x0 + rowb) : g_zpad) + kq * 8;
      srcB[r][1] = (v ? (x1 + rowb) : g_zpad) + kq * 8;
    }
  };

  const int wvb = wv * 1024;  // wave-uniform byte base (lane*16 auto)
  auto stage = [&](int chunk, int bi) {
    const int tap = chunk >> 3, cg = chunk & 7;
    if (tap != ptap) retap(tap);
    char* bufb = (char*)smem[bi];
    const ushort_t* ap = wp + ((size_t)(chunk * 4 + coT) << 12) + tid * 8;
    gload16(ap,        bufb + wvb);                        // sA pl0
    gload16(ap + 2048, bufb + 4096 + wvb);                 // sA pl1
    const int ko = cg * 32;
    gload16(srcB[0][0] + ko, bufb + 8192 + wvb);           // sB pl0 rows 0-63
    gload16(srcB[1][0] + ko, bufb + 8192 + 4096 + wvb);    // sB pl0 rows 64-127
    gload16(srcB[0][1] + ko, bufb + 16384 + wvb);          // sB pl1 rows 0-63
    gload16(srcB[1][1] + ko, bufb + 16384 + 4096 + wvb);   // sB pl1 rows 64-127
  };
  auto compute = [&](const ushort_t* buf) {
    const ushort_t* sA = buf;
    const ushort_t* sB = buf + 4096;
    short8 af[4][2], bf[2][2];
#pragma unroll
    for (int m = 0; m < 4; ++m)
#pragma unroll
      for (int pl = 0; pl < 2; ++pl)
        af[m][pl] = *(const short8*)(sA + pl * 2048 + (m * 16 + l15) * 32 + q * 8);
#pragma unroll
    for (int n = 0; n < 2; ++n)
#pragma unroll
      for (int pl = 0; pl < 2; ++pl)
        bf[n][pl] = *(const short8*)(sB + pl * 4096 + (wv * 32 + n * 16 + l15) * 32 + q * 8);
#pragma unroll
    for (int m = 0; m < 4; ++m)
#pragma unroll
      for (int n = 0; n < 2; ++n) {
        acc[m][n] = __builtin_amdgcn_mfma_f32_16x16x32_bf16(af[m][0], bf[n][0], acc[m][n], 0, 0, 0);
        acc[m][n] = __builtin_amdgcn_mfma_f32_16x16x32_bf16(af[m][0], bf[n][1], acc[m][n], 0, 0, 0);
        acc[m][n] = __builtin_amdgcn_mfma_f32_16x16x32_bf16(af[m][1], bf[n][0], acc[m][n], 0, 0, 0);
      }
  };

  stage(CH0, 0);
  __syncthreads();
  int cur = 0;
  for (int c = CH0; c < CH1; ++c) {
    if (c + 1 < CH1) stage(c + 1, cur ^ 1);   // DMA in flight under compute
    compute(smem[cur]);
    __syncthreads();                           // drains DMA; 1 barrier/chunk
    cur ^= 1;
  }

  // plain stores to this kz's private partial slice (deterministic)
  float* pz = part + ((size_t)blockIdx.z << 21);
#pragma unroll
  for (int m = 0; m < 4; ++m) {
#pragma unroll
    for (int n = 0; n < 2; ++n) {
#pragma unroll
      for (int r = 0; r < 4; ++r) {
        const int co_l = m * 16 + q * 4 + r;
        const int px_l = wv * 32 + n * 16 + l15;
        const int px = pxT * 128 + px_l;
        const int img = px >> 10, pp = px & 1023;
        const size_t ha = ((size_t)(img * 256 + coT * 64 + co_l)) * 1024 + pp;
        pz[ha] = acc[m][n][r];
      }
    }
  }
}

// ---------- epilogue for split convs ----------
// v = p0 + p1 + bias (fixed order -> deterministic).
// WH (conv2): v=relu(v); h32=v; split v.   !WH (3x3): split relu(v).
template<bool WH>
__global__ __launch_bounds__(256) void k_enc_epi(
    const float* __restrict__ part, float* __restrict__ h32,
    ushort_t* __restrict__ s0, ushort_t* __restrict__ s1,
    const float* __restrict__ bias)
{
  const int px = blockIdx.x * 256 + threadIdx.x;  // 8192
  const int co0 = blockIdx.y * 16;
  const int img = px >> 10, pp = px & 1023;
  const float* part1 = part + (1u << 21);
  uint p0[8], p1[8];
#pragma unroll
  for (int i = 0; i < 8; ++i) {
    size_t ha = ((size_t)(img * 256 + co0 + 2 * i)) * 1024 + pp;
    size_t hb = ha + 1024;
    float va = part[ha] + part1[ha] + bias[co0 + 2 * i];
    float vb = part[hb] + part1[hb] + bias[co0 + 2 * i + 1];
    float sa, sb;
    if (WH) {
      va = fmaxf(va, 0.f); vb = fmaxf(vb, 0.f);
      h32[ha] = va; h32[hb] = vb; sa = va; sb = vb;
    } else { sa = fmaxf(va, 0.f); sb = fmaxf(vb, 0.f); }
    ushort_t a0 = f2bf(sa), b0 = f2bf(sb);
    p0[i] = (uint)a0 | ((uint)b0 << 16);
    p1[i] = (uint)f2bf(sa - bf2f(a0)) | ((uint)f2bf(sb - bf2f(b0)) << 16);
  }
  ushort_t* d0 = s0 + (size_t)px * 256 + co0;
  ushort_t* d1 = s1 + (size_t)px * 256 + co0;
  uint4 v0a; v0a.x = p0[0]; v0a.y = p0[1]; v0a.z = p0[2]; v0a.w = p0[3];
  uint4 v0b; v0b.x = p0[4]; v0b.y = p0[5]; v0b.z = p0[6]; v0b.w = p0[7];
  uint4 v1a; v1a.x = p1[0]; v1a.y = p1[1]; v1a.z = p1[2]; v1a.w = p1[3];
  uint4 v1b; v1b.x = p1[4]; v1b.y = p1[5]; v1b.z = p1[6]; v1b.w = p1[7];
  *(uint4*)d0 = v0a; *(uint4*)(d0 + 8) = v0b;
  *(uint4*)d1 = v1a; *(uint4*)(d1 + 8) = v1b;
}

// ---------- residual 1x1 MFMA (fused epilogue) ----------
// h += conv1x1(x) + bias; write h32; if WS also split(relu(h)) via LDS shuffle.
// R5: global_load_lds staging (8 chunks), linear LDS.
template<bool WS>
__global__ __launch_bounds__(256) void k_enc_mfma(
    const ushort_t* __restrict__ x0, const ushort_t* __restrict__ x1,
    const ushort_t* __restrict__ wp, const float* __restrict__ bias,
    float* __restrict__ h32, ushort_t* __restrict__ sp0, ushort_t* __restrict__ sp1)
{
  __shared__ ushort_t smem[24576];   // dbuf 2x12288; WS epilogue reuses [0,18432)
  const int tid = threadIdx.x, lane = tid & 63, wv = tid >> 6;
  const int l15 = lane & 15, q = lane >> 4;
  const int pxT = blockIdx.x, coT = blockIdx.y;
  f32x4 acc[4][2];
#pragma unroll
  for (int m = 0; m < 4; ++m)
#pragma unroll
    for (int n = 0; n < 2; ++n) acc[m][n] = (f32x4){0.f, 0.f, 0.f, 0.f};

  const int r0 = tid >> 2, kq = tid & 3;
  const ushort_t* srcB[2][2];
#pragma unroll
  for (int r = 0; r < 2; ++r) {
    size_t rowb = ((size_t)(pxT * 128 + r0 + r * 64)) << 8;
    srcB[r][0] = x0 + rowb + kq * 8;
    srcB[r][1] = x1 + rowb + kq * 8;
  }
  const int wvb = wv * 1024;
  auto stage = [&](int c, int bi) {
    char* bufb = (char*)(smem + bi * 12288);
    const ushort_t* ap = wp + ((size_t)(c * 4 + coT) << 12) + tid * 8;
    gload16(ap,        bufb + wvb);
    gload16(ap + 2048, bufb + 4096 + wvb);
    const int ko = c * 32;
    gload16(srcB[0][0] + ko, bufb + 8192 + wvb);
    gload16(srcB[1][0] + ko, bufb + 8192 + 4096 + wvb);
    gload16(srcB[0][1] + ko, bufb + 16384 + wvb);
    gload16(srcB[1][1] + ko, bufb + 16384 + 4096 + wvb);
  };
  auto compute = [&](const ushort_t* buf) {
    const ushort_t* sA = buf;
    const ushort_t* sB = buf + 4096;
    short8 af[4][2], bf[2][2];
#pragma unroll
    for (int m = 0; m < 4; ++m)
#pragma unroll
      for (int pl = 0; pl < 2; ++pl)
        af[m][pl] = *(const short8*)(sA + pl * 2048 + (m * 16 + l15) * 32 + q * 8);
#pragma unroll
    for (int n = 0; n < 2; ++n)
#pragma unroll
      for (int pl = 0; pl < 2; ++pl)
        bf[n][pl] = *(const short8*)(sB + pl * 4096 + (wv * 32 + n * 16 + l15) * 32 + q * 8);
#pragma unroll
    for (int m = 0; m < 4; ++m)
#pragma unroll
      for (int n = 0; n < 2; ++n) {
        acc[m][n] = __builtin_amdgcn_mfma_f32_16x16x32_bf16(af[m][0], bf[n][0], acc[m][n], 0, 0, 0);
        acc[m][n] = __builtin_amdgcn_mfma_f32_16x16x32_bf16(af[m][0], bf[n][1], acc[m][n], 0, 0, 0);
        acc[m][n] = __builtin_amdgcn_mfma_f32_16x16x32_bf16(af[m][1], bf[n][0], acc[m][n], 0, 0, 0);
      }
  };

  stage(0, 0);
  __syncthreads();
  int cur = 0;
  for (int c = 0; c < 8; ++c) {
    if (c + 1 < 8) stage(c + 1, cur ^ 1);
    compute(smem + cur * 12288);
    __syncthreads();
    cur ^= 1;
  }

#pragma unroll
  for (int m = 0; m < 4; ++m) {
#pragma unroll
    for (int n = 0; n < 2; ++n) {
#pragma unroll
      for (int r = 0; r < 4; ++r) {
        const int co_l = m * 16 + q * 4 + r;
        const int px_l = wv * 32 + n * 16 + l15;
        float v = acc[m][n][r] + bias[coT * 64 + co_l];
        const int px = pxT * 128 + px_l;
        const int img = px >> 10, pp = px & 1023;
        const size_t ha = ((size_t)(img * 256 + coT * 64 + co_l)) * 1024 + pp;
        v += h32[ha];
        h32[ha] = v;
        if (WS) {
          float sv = fmaxf(v, 0.f);
          ushort_t b0 = f2bf(sv);
          smem[px_l * 72 + co_l] = b0;
          smem[9216 + px_l * 72 + co_l] = f2bf(sv - bf2f(b0));
        }
      }
    }
  }
  if (WS) {
    __syncthreads();
#pragma unroll
    for (int i = 0; i < 8; ++i) {
      int idx = tid + 256 * i;
      int pl = idx >> 10, w2 = idx & 1023, pxl = w2 >> 3, g = w2 & 7;
      uint4 vv = *(const uint4*)(smem + pl * 9216 + pxl * 72 + g * 8);
      ushort_t* dst = (pl ? sp1 : sp0) + ((size_t)(pxT * 128 + pxl)) * 256 + coT * 64 + g * 8;
      *(uint4*)dst = vv;
    }
  }
}

// ---------- 1x1 conv fp32 (to_z only) ----------
__global__ __launch_bounds__(256) void k_conv1x1(
    const float* __restrict__ in, float* __restrict__ out,
    const float* __restrict__ wT, const float* __restrict__ bias,
    int CI, int CO, int P)
{
  const int p = blockIdx.x * 256 + threadIdx.x;
  const int cob = blockIdx.y * 16;
  const int n = blockIdx.z;
  const float* inN = in + (size_t)n * CI * P + p;
  float acc[16];
#pragma unroll
  for (int i = 0; i < 16; ++i) acc[i] = bias[cob + i];
  const float* wr = wT + cob;
#pragma unroll 4
  for (int ci = 0; ci < CI; ++ci) {
    float iv = inN[(size_t)ci * P];
    const float* w = wr + (size_t)ci * CO;  // uniform
#pragma unroll
    for (int i = 0; i < 16; ++i) acc[i] = fmaf(iv, w[i], acc[i]);
  }
  float* outN = out + (size_t)n * CO * P + p;
#pragma unroll
  for (int i = 0; i < 16; ++i) outN[(size_t)(cob + i) * P] = acc[i];
}

// ---------- VQ partial: 16 chunks of 32 codes; per-j math identical ----------
__global__ __launch_bounds__(256) void k_vq_part(
    const float* __restrict__ z_e, const float* __restrict__ cb,
    const float* __restrict__ cnorm, float* __restrict__ pbest, int* __restrict__ pbid)
{
  int g = blockIdx.x * 256 + threadIdx.x;  // 8192 points
  int chunk = blockIdx.y;                  // 16 chunks
  int img = g >> 10, p = g & 1023;
  const float* zp = z_e + (size_t)img * 64 * 1024 + p;
  float z[64];
#pragma unroll
  for (int c = 0; c < 64; ++c) z[c] = zp[(size_t)c * 1024];
  float best = 3.4e38f; int bid = chunk << 5;
  const int j0 = chunk << 5;
  for (int j = j0; j < j0 + 32; ++j) {
    const float* cj = cb + j * 64;  // uniform -> scalar loads
    float m = 0.f;
#pragma unroll
    for (int c = 0; c < 64; ++c) m = fmaf(z[c], cj[c], m);
    float d = fmaf(-2.f, m, cnorm[j]);
    if (d < best) { best = d; bid = j; }  // strict <: first-min within chunk
  }
  pbest[chunk * 8192 + g] = best;
  pbid[chunk * 8192 + g] = bid;
}

// ---------- VQ reduce: argmin across chunks (ascending -> np.argmin) + e_k ----------
__global__ __launch_bounds__(256) void k_vq_reduce(
    const float* __restrict__ pbest, const int* __restrict__ pbid,
    const float* __restrict__ cb, float* __restrict__ ids_f, float* __restrict__ ek)
{
  int g = blockIdx.x * 256 + threadIdx.x;  // 8192
  float best = 3.4e38f; int bid = 0;
#pragma unroll
  for (int ch = 0; ch < 16; ++ch) {
    float d = pbest[ch * 8192 + g];
    int b = pbid[ch * 8192 + g];
    if (d < best) { best = d; bid = b; }
  }
  ids_f[g] = (float)bid;
  int img = g >> 10, p = g & 1023;
  const float* cbid = cb + bid * 64;
  float* ekp = ek + (size_t)img * 64 * 1024 + p;
#pragma unroll
  for (int c = 0; c < 64; ++c) ekp[(size_t)c * 1024] = cbid[c];
}

// ---------- from_z 1x1 (64->256) + relu -> NHWC bf16 ----------
__global__ __launch_bounds__(256) void k_from_z(
    const float* __restrict__ ek, ushort_t* __restrict__ nhwc,
    const float* __restrict__ wT, const float* __restrict__ bias)
{
  const int p = blockIdx.x * 256 + threadIdx.x;  // 0..1023
  const int co0 = blockIdx.y * 16;
  const int n = blockIdx.z;
  const float* inN = ek + (size_t)n * 64 * 1024 + p;
  float acc[16];
#pragma unroll
  for (int i = 0; i < 16; ++i) acc[i] = bias[co0 + i];
#pragma unroll 4
  for (int ci = 0; ci < 64; ++ci) {
    float iv = inN[(size_t)ci * 1024];
    const float* w = wT + (size_t)ci * 256 + co0;  // uniform
#pragma unroll
    for (int i = 0; i < 16; ++i) acc[i] = fmaf(iv, w[i], acc[i]);
  }
  uint pk[8];
#pragma unroll
  for (int i = 0; i < 8; ++i) {
    ushort_t lo = f2bf(fmaxf(acc[2 * i], 0.f));
    ushort_t hi = f2bf(fmaxf(acc[2 * i + 1], 0.f));
    pk[i] = (uint)lo | ((uint)hi << 16);
  }
  ushort_t* op = nhwc + (((size_t)n * 1024 + p) * 256 + co0);
  uint4 v0; v0.x = pk[0]; v0.y = pk[1]; v0.z = pk[2]; v0.w = pk[3];
  uint4 v1; v1.x = pk[4]; v1.y = pk[5]; v1.z = pk[6]; v1.w = pk[7];
  *(uint4*)(op) = v0;
  *(uint4*)(op + 8) = v1;
}

// ---------- t1 convtranspose 4x4 s2 p1, 256->256, bf16 MFMA, relu -> bf16 NHWC
// R5: global_load_lds staging, linear LDS; R3 sync structure.
__global__ __launch_bounds__(256) void k_mfma_t1(
    const ushort_t* __restrict__ nhwc, const ushort_t* __restrict__ wb,
    const float* __restrict__ bias, ushort_t* __restrict__ t1o)
{
  __shared__ ushort_t smem[2][8192];   // per buf: sA 4096 us | sB 4096 us
  const int tid = threadIdx.x;
  const int lane = tid & 63;
  const int wv = tid >> 6;
  const int wm = wv & 1, wn = wv >> 1;
  const int l15 = lane & 15, q = lane >> 4;
  const int pxT = blockIdx.x, coT = blockIdx.y, par = blockIdx.z;
  const int ry = par & 1, rx = (par >> 1) & 1;
  const int pxbase = pxT * 128;
  const int img = pxbase >> 10;
  f32x4 acc[4][4];
#pragma unroll
  for (int i = 0; i < 4; ++i)
#pragma unroll
    for (int j = 0; j < 4; ++j) acc[i][j] = (f32x4){0.f, 0.f, 0.f, 0.f};

  const int srow = tid >> 2, kg = tid & 3;
  int bu2[2], bv2[2];
#pragma unroll
  for (int r = 0; r < 2; ++r) {
    int px = pxbase + srow + r * 64;
    bu2[r] = (px >> 5) & 31; bv2[r] = px & 31;
  }
  const ushort_t* nb[2];
  int ptap = -1;
  auto retap = [&](int tap) {
    ptap = tap;
    int ta = tap >> 1, tb = tap & 1;
#pragma unroll
    for (int r = 0; r < 2; ++r) {
      int iy = bu2[r] + ry - ta, ix = bv2[r] + rx - tb;
      bool v = ((unsigned)iy < 32u) && ((unsigned)ix < 32u);
      nb[r] = (v ? (nhwc + (((size_t)(img * 1024 + iy * 32 + ix)) << 8)) : g_zpad) + kg * 8;
    }
  };
  const int wvb = wv * 1024;
  auto stage = [&](int c, int bi) {
    const int tap = c >> 3, c8 = c & 7;
    if (tap != ptap) retap(tap);
    char* bufb = (char*)smem[bi];
    const ushort_t* Abase = wb + ((size_t)((par * 4 + tap) * 8 + c8) << 13) + coT * 4096 + tid * 8;
    gload16(Abase,        bufb + wvb);
    gload16(Abase + 2048, bufb + 4096 + wvb);
    const int ko = c8 * 32;
    gload16(nb[0] + ko, bufb + 8192 + wvb);
    gload16(nb[1] + ko, bufb + 8192 + 4096 + wvb);
  };
  auto compute = [&](const ushort_t* buf) {
    const ushort_t* sA = buf;
    const ushort_t* sB = buf + 4096;
    short8 af[4], bfr[4];
#pragma unroll
    for (int i = 0; i < 4; ++i)
      af[i] = *(const short8*)(sA + (wm * 64 + i * 16 + l15) * 32 + q * 8);
#pragma unroll
    for (int j = 0; j < 4; ++j)
      bfr[j] = *(const short8*)(sB + (wn * 64 + j * 16 + l15) * 32 + q * 8);
#pragma unroll
    for (int i = 0; i < 4; ++i)
#pragma unroll
      for (int j = 0; j < 4; ++j)
        acc[i][j] = __builtin_amdgcn_mfma_f32_16x16x32_bf16(af[i], bfr[j], acc[i][j], 0, 0, 0);
  };

  stage(0, 0);
  __syncthreads();
  int cur = 0;
  for (int c = 0; c < 32; ++c) {
    if (c + 1 < 32) stage(c + 1, cur ^ 1);
    compute(smem[cur]);
    __syncthreads();
    cur ^= 1;
  }

#pragma unroll
  for (int i = 0; i < 4; ++i) {
    int co = coT * 128 + wm * 64 + i * 16 + q * 4;
#pragma unroll
    for (int j = 0; j < 4; ++j) {
      int px = pxbase + wn * 64 + j * 16 + l15;
      int u = (px >> 5) & 31, vv = px & 31;
      int oy = 2 * u + ry, ox = 2 * vv + rx;
      ushort_t e0 = f2bf(fmaxf(acc[i][j][0] + bias[co + 0], 0.f));
      ushort_t e1 = f2bf(fmaxf(acc[i][j][1] + bias[co + 1], 0.f));
      ushort_t e2 = f2bf(fmaxf(acc[i][j][2] + bias[co + 2], 0.f));
      ushort_t e3 = f2bf(fmaxf(acc[i][j][3] + bias[co + 3], 0.f));
      uint2 pk; pk.x = (uint)e0 | ((uint)e1 << 16); pk.y = (uint)e2 | ((uint)e3 << 16);
      *(uint2*)(t1o + ((size_t)(img * 4096 + oy * 64 + ox) * 256 + co)) = pk;
    }
  }
}

// ---------- t2 convtranspose 4x4 s2 p1, 256->3, bf16 MFMA, sigmoid ----------
__global__ __launch_bounds__(256) void k_mfma_t2(
    const ushort_t* __restrict__ t1o, const ushort_t* __restrict__ wb,
    const float* __restrict__ bias, float* __restrict__ out)
{
  __shared__ ushort_t sA2[256 * 32];
  __shared__ ushort_t sB2[16 * 32];
  const int tid = threadIdx.x, lane = tid & 63, wv = tid >> 6;
  const int l15 = lane & 15, q = lane >> 4;
  const int pxb = blockIdx.x * 256;
  const int par = blockIdx.y;
  const int ry = par & 1, rx = (par >> 1) & 1;
  f32x4 acc[4];
#pragma unroll
  for (int m = 0; m < 4; ++m) acc[m] = (f32x4){0.f, 0.f, 0.f, 0.f};
  const int kg = tid & 3;
  const int ssw = ((tid >> 2) & 7) << 3;
  size_t rb[4]; bool rv[4];
  for (int chunk = 0; chunk < 32; ++chunk) {
    const int tap = chunk >> 3, cg = chunk & 7;
    const int a = tap >> 1, b = tap & 1;
    if ((chunk & 7) == 0) {
#pragma unroll
      for (int i = 0; i < 4; ++i) {
        int row = (tid >> 2) + 64 * i;
        int px = pxb + row;
        int img = px >> 12, p = px & 4095, u = p >> 6, v = p & 63;
        int iy = u + ry - a, ix = v + rx - b;
        rv[i] = ((unsigned)iy < 64u) && ((unsigned)ix < 64u);
        rb[i] = ((size_t)(img * 4096 + iy * 64 + ix)) << 8;
      }
    }
    uint4 av[4];
#pragma unroll
    for (int i = 0; i < 4; ++i) {
      if (rv[i]) av[i] = *(const uint4*)(t1o + rb[i] + cg * 32 + kg * 8);
      else { av[i].x = 0; av[i].y = 0; av[i].z = 0; av[i].w = 0; }
    }
    uint4 bv;
    if (tid < 64) bv = *(const uint4*)(wb + ((size_t)(par * 32 + chunk)) * 512 + tid * 8);
    __syncthreads();
#pragma unroll
    for (int i = 0; i < 4; ++i)
      *(uint4*)(sA2 + (((((tid >> 2) + 64 * i) * 32) + kg * 8) ^ ssw)) = av[i];
    if (tid < 64) *(uint4*)(sB2 + ((tid * 8) ^ ssw)) = bv;
    __syncthreads();
    short8 bf = *(const short8*)(sB2 + ((l15 * 32 + q * 8) ^ ((l15 & 7) << 3)));
#pragma unroll
    for (int m = 0; m < 4; ++m) {
      const int row = wv * 64 + m * 16 + l15;
      short8 af = *(const short8*)(sA2 + ((row * 32 + q * 8) ^ ((row & 7) << 3)));
      acc[m] = __builtin_amdgcn_mfma_f32_16x16x32_bf16(af, bf, acc[m], 0, 0, 0);
    }
    __syncthreads();
  }
  const int co = l15;
  if (co < 3) {
    float bco = bias[co];
#pragma unroll
    for (int m = 0; m < 4; ++m) {
#pragma unroll
      for (int r = 0; r < 4; ++r) {
        int px = pxb + wv * 64 + m * 16 + q * 4 + r;
        int img = px >> 12, p = px & 4095, u = p >> 6, v = p & 63;
        size_t addr = ((size_t)(img * 3 + co)) * 16384 + (2 * u + ry) * 128 + (2 * v + rx);
        out[addr] = 1.f / (1.f + expf(-(acc[m][r] + bco)));
      }
    }
  }
}

// ---------------------------------------------------------------------------
extern "C" void kernel_launch(void* const* d_in, const int* in_sizes, int n_in,
                              void* d_out, int out_size, void* d_ws, size_t ws_size,
                              hipStream_t stream) {
  (void)in_sizes; (void)n_in; (void)out_size; (void)ws_size;
  const float* x      = (const float*)d_in[0];
  const float* c1_w   = (const float*)d_in[1];
  const float* c1_b   = (const float*)d_in[2];
  const float* c2_w   = (const float*)d_in[3];
  const float* c2_b   = (const float*)d_in[4];
  const float* r0_w3  = (const float*)d_in[5];
  const float* r0_b3  = (const float*)d_in[6];
  const float* r0_w1  = (const float*)d_in[7];
  const float* r0_b1  = (const float*)d_in[8];
  const float* r1_w3  = (const float*)d_in[9];
  const float* r1_b3  = (const float*)d_in[10];
  const float* r1_w1  = (const float*)d_in[11];
  const float* r1_b1  = (const float*)d_in[12];
  const float* to_z_w = (const float*)d_in[13];
  const float* to_z_b = (const float*)d_in[14];
  const float* cb     = (const float*)d_in[15];
  const float* from_z_w = (const float*)d_in[16];
  const float* from_z_b = (const float*)d_in[17];
  const float* t1_w   = (const float*)d_in[18];
  const float* t1_b   = (const float*)d_in[19];
  const float* t2_w   = (const float*)d_in[20];
  const float* t2_b   = (const float*)d_in[21];

  float* wsf = (float*)d_ws;
  // Era-choreographed regions (float offsets) — see R3 comments; unchanged.
  ushort_t* xs1p0 = (ushort_t*)(wsf + 0);
  ushort_t* xs1p1 = (ushort_t*)(wsf + 4194304);
  float*    cp0   = wsf + 8388608;               // conv2 partial kz0 (= h32 slot)
  float*    h32   = wsf + 8388608;
  float*    qp0   = wsf + 4194304;               // 3x3 partials (xs1p1 slot, dead)
  ushort_t* sE0   = (ushort_t*)(wsf + 0);        // split ping [0,1.05M)
  ushort_t* sE1   = (ushort_t*)(wsf + 1048576);  // split ping [1.05,2.1M)
  ushort_t* sF0   = (ushort_t*)(wsf + 2097152);  // split pong [2.1,3.15M)
  ushort_t* sF1   = (ushort_t*)(wsf + 3145728);  // split pong [3.15,4.19M)
  float*    pbest = wsf + 0;                     // vq-era
  int*      pbid  = (int*)(wsf + 131072);        // vq-era
  ushort_t* t1out = (ushort_t*)(wsf + 2097152);  // dec-era [2.1M, 6.29M)
  ushort_t* decn  = (ushort_t*)(wsf + 6291456);  // dec-era [6.29M, 7.34M)
  ushort_t* wp_c2   = (ushort_t*)(wsf + 12582912);
  ushort_t* wp_r0w3 = (ushort_t*)(wsf + 13631488);
  ushort_t* wp_r1w3 = (ushort_t*)(wsf + 14221312);
  ushort_t* wp_r0w1 = (ushort_t*)(wsf + 14811136);
  ushort_t* wp_r1w1 = (ushort_t*)(wsf + 14876672);
  float*    wt_c1   = wsf + 14942208;
  float*    wt_toz  = wsf + 14954496;
  float*    wt_fromz= wsf + 14970880;
  ushort_t* t1wb    = (ushort_t*)(wsf + 14987264);
  ushort_t* w2pk    = (ushort_t*)(wsf + 15511552);
  float*    cnorm   = wsf + 15544320;

  float* out_img = (float*)d_out;        // 393216
  float* z_e_out = out_img + 393216;     // 524288
  float* e_k_out = z_e_out + 524288;     // 524288
  float* ids_out = e_k_out + 524288;     // 8192 (stored as float)

  // ---- weight prep ----
  k_transpose_w<<<48, 256, 0, stream>>>(c1_w, wt_c1, 256, 48);
  k_transpose_w<<<64, 256, 0, stream>>>(to_z_w, wt_toz, 64, 256);
  k_transpose_w<<<64, 256, 0, stream>>>(from_z_w, wt_fromz, 256, 64);
  k_prep_enc<0><<<8192, 256, 0, stream>>>(c2_w,  wp_c2,   128 << 14);
  k_prep_enc<1><<<4608, 256, 0, stream>>>(r0_w3, wp_r0w3, 72 << 14);
  k_prep_enc<1><<<4608, 256, 0, stream>>>(r1_w3, wp_r1w3, 72 << 14);
  k_prep_enc<2><<<512,  256, 0, stream>>>(r0_w1, wp_r0w1, 8 << 14);
  k_prep_enc<2><<<512,  256, 0, stream>>>(r1_w1, wp_r1w1, 8 << 14);
  k_prep_t1w<<<4096, 256, 0, stream>>>(t1_w, t1wb);
  k_prep_t2w<<<256, 256, 0, stream>>>(t2_w, w2pk);
  k_prep_cb<<<2, 256, 0, stream>>>(cb, cnorm);

  // ---- encoder ----
  k_conv1_split<<<dim3(64, 4, 8), 256, 0, stream>>>(x, xs1p0, xs1p1, wt_c1, c1_b);
  // conv2: plain-store partials cp0/cp1, epilogue: sum+relu -> h32 + splits
  k_enc_mfma_split<0><<<dim3(64, 4, 2), 256, 0, stream>>>(xs1p0, xs1p1, wp_c2, cp0);
  k_enc_epi<true><<<dim3(32, 16), 256, 0, stream>>>(cp0, h32, sE0, sE1, c2_b);
  // r0 w3
  k_enc_mfma_split<1><<<dim3(64, 4, 2), 256, 0, stream>>>(sE0, sE1, wp_r0w3, qp0);
  k_enc_epi<false><<<dim3(32, 16), 256, 0, stream>>>(qp0, nullptr, sE0, sE1, r0_b3);
  // r0 w1: h += conv; write h32 + split(relu(h))
  k_enc_mfma<true ><<<dim3(64, 4), 256, 0, stream>>>(
      sE0, sE1, wp_r0w1, r0_b1, h32, sF0, sF1);
  // r1 w3
  k_enc_mfma_split<1><<<dim3(64, 4, 2), 256, 0, stream>>>(sF0, sF1, wp_r1w3, qp0);
  k_enc_epi<false><<<dim3(32, 16), 256, 0, stream>>>(qp0, nullptr, sE0, sE1, r1_b3);
  // r1 w1: h += conv; write h32 only
  k_enc_mfma<false><<<dim3(64, 4), 256, 0, stream>>>(
      sE0, sE1, wp_r1w1, r1_b1, h32, nullptr, nullptr);
  // to_z (fp32)
  k_conv1x1<<<dim3(4, 4, 8), 256, 0, stream>>>(h32, z_e_out, wt_toz, to_z_b, 256, 64, 1024);

  // ---- VQ (chunk-parallel; bit-identical argmin) ----
  k_vq_part<<<dim3(32, 16), 256, 0, stream>>>(z_e_out, cb, cnorm, pbest, pbid);
  k_vq_reduce<<<32, 256, 0, stream>>>(pbest, pbid, cb, ids_out, e_k_out);

  // ---- decoder (bf16) ----
  k_from_z<<<dim3(4, 16, 8), 256, 0, stream>>>(e_k_out, decn, wt_fromz, from_z_b);
  k_mfma_t1<<<dim3(64, 2, 4), 256, 0, stream>>>(decn, t1wb, t1_b, t1out);
  k_mfma_t2<<<dim3(128, 4), 256, 0, stream>>>(t1out, w2pk, t2_b, out_img);
}